// Round 8
// baseline (124.708 us; speedup 1.0000x reference)
//
#include <hip/hip_runtime.h>
#include <math.h>

#define NB 4
#define NH 512
#define NW 512
#define NC 19
#define NPIX (NB*NH*NW)
#define TS 16
#define NLAD 128
#define INF6 1.0e6f
#define MAXDIS 1.0e5f
#define NWRD 16          // 512 rows / 32 bits
#define NREP 8           // histogram replicas
#define HSTRIDE 132      // padded per-replica stride (129 bins)
#define NSEG 128         // compaction segments
#define SEGCAP 512       // entries per segment (expected max ~250)
#define NZERO (NREP*HSTRIDE + NSEG)   // hist + cnts words zeroed by bound blk 0

// ---------------------------------------------------------------------------
// Stage 1a: boundary bitmasks. One thread per (b, word, column).
// Also zero-fills cearr (4 MB, coalesced float4) and hist+cnts (block 0) --
// replaces all hipMemsetAsync dispatches. No flags/atomics needed anymore.
// ---------------------------------------------------------------------------
__global__ __launch_bounds__(64) void bound_kernel(const int* __restrict__ tgt,
                                                   unsigned int* __restrict__ maskw,
                                                   float4* __restrict__ cearr4,
                                                   unsigned int* __restrict__ zbuf) {
    int cidx = blockIdx.x * 64 + threadIdx.x;           // [b][w][j], 32768 total
    const float4 z4 = make_float4(0.f, 0.f, 0.f, 0.f);
#pragma unroll
    for (int k = 0; k < 8; ++k) cearr4[cidx + k * 32768] = z4;   // NPIX/4 entries
    if (blockIdx.x == 0) {
        for (int k = threadIdx.x; k < NZERO; k += 64) zbuf[k] = 0u;
    }
    int j = cidx & (NW - 1);
    int w = (cidx >> 9) & (NWRD - 1);
    int b = cidx >> 13;
    const int* t = tgt + (size_t)b * NH * NW;
    unsigned int mask = 0u;
    int i0 = w * 32;
    int cur = t[(size_t)i0 * NW + j];
    for (int k = 0; k < 32; ++k) {
        int i = i0 + k;
        int nxt = (i + 1 < NH) ? t[(size_t)(i + 1) * NW + j] : cur;
        bool bnd = (cur == 255);
        if (i + 1 < NH && nxt != cur) bnd = true;
        if (j + 1 < NW && t[(size_t)i * NW + j + 1] != cur) bnd = true;
        if (bnd) mask |= (1u << k);
        cur = nxt;
    }
    maskw[cidx] = mask;
}

// ---------------------------------------------------------------------------
// Stage 1b+2 fused: block per row. Stage the batch's full column-mask set in
// LDS (runtime word index must be LDS, not regs), nearest-set-bit -> G^2 in
// LDS, then the row min-plus transform. any_b derived block-locally (each
// block reads the whole batch mask) -- no flags buffer.
// ---------------------------------------------------------------------------
__global__ __launch_bounds__(512) void vdistrow_kernel(const unsigned int* __restrict__ maskw,
                                                       float* __restrict__ dist) {
    __shared__ unsigned int smw[NWRD][NW];   // 32 KB: all masks of this batch
    __shared__ float s[NW];
    __shared__ unsigned int anyw[8];
    const int tid = threadIdx.x;             // = column j
    const int row = blockIdx.x;              // b*NH + i
    const int b = row >> 9;
    const int i = row & (NH - 1);
    const unsigned int* mcol = maskw + (size_t)b * NWRD * NW;
    unsigned int acc = 0u;
#pragma unroll
    for (int w = 0; w < NWRD; ++w) {
        unsigned int v = mcol[w * NW + tid];
        smw[w][tid] = v;
        acc |= v;
    }
    unsigned long long bal = __ballot(acc != 0u);
    if ((tid & 63) == 0) anyw[tid >> 6] = (bal != 0ull) ? 1u : 0u;

    const int wi = i >> 5, bi = i & 31;
    int down = 1 << 20;
    unsigned int m = smw[wi][tid] & ((2u << bi) - 1u);   // bits 0..bi
    if (m) down = bi - (31 - __clz(m));
    else {
        for (int w = wi - 1; w >= 0; --w) {
            unsigned int mm = smw[w][tid];
            if (mm) { down = bi + 32 * (wi - w) - (31 - __clz(mm)); break; }
        }
    }
    int up = 1 << 20;
    unsigned int mu = smw[wi][tid] & ~((1u << bi) - 1u); // bits bi..31
    if (mu) up = (__ffs(mu) - 1) - bi;
    else {
        for (int w = wi + 1; w < NWRD; ++w) {
            unsigned int mm = smw[w][tid];
            if (mm) { up = 32 * (w - wi) + (__ffs(mm) - 1) - bi; break; }
        }
    }
    int gi = min(down, up);
    float G = (gi >= (1 << 20)) ? INF6 : (float)gi;
    s[tid] = G * G;
    __syncthreads();
    bool has = (anyw[0] | anyw[1] | anyw[2] | anyw[3] |
                anyw[4] | anyw[5] | anyw[6] | anyw[7]) != 0u;
    float best = s[tid];
    for (int r = 1; r < NW; ++r) {
        float rr = (float)(r * r);
        if (rr >= best) break;
        int jl = tid - r, jr = tid + r;
        if (jl >= 0) best = fminf(best, s[jl] + rr);
        if (jr < NW) best = fminf(best, s[jr] + rr);
    }
    dist[(size_t)row * NW + tid] = has ? fmaxf(sqrtf(best) - 1.f, 0.f) : 0.f;
}

// ---------------------------------------------------------------------------
// Stage 3: kl map + fused 8-replica histogram. LSE computed IN-BLOCK from the
// staged tiles (513 tasks over 256 threads) -- no lsem pass, logits read once
// per role. Bit-identical LSE formula everywhere.
// ---------------------------------------------------------------------------
__global__ __launch_bounds__(256) void klhist_kernel(const float* __restrict__ logits,
                                                     float* __restrict__ klb,
                                                     unsigned int* __restrict__ hist) {
    __shared__ float4 Lc4[1221];                // up to 257*19 floats
    __shared__ float4 Ld4[1216];                // 256*19 floats
    __shared__ float Mc[258];
    __shared__ float Md[256];
    __shared__ float lad[NLAD];
    __shared__ unsigned int lh[NLAD + 1];
    const int tid = threadIdx.x;
    const int cid = blockIdx.x;
    const int j0 = (cid & 1) * 256;
    const int i = (cid >> 1) & (NH - 1);
    const int b = cid >> 10;

    if (tid == 0) {
        float e = 1e-5f;
        for (int k = 0; k < NLAD; ++k) { lad[k] = e; e *= 1.2f; }
    }
    if (tid < NLAD + 1) lh[tid] = 0u;

    const size_t rowpix = (size_t)(b * NH + i) * NW + j0;
    const float4* src = reinterpret_cast<const float4*>(logits + rowpix * NC);
    const int n4c = (j0 == 0) ? 1221 : 1216;
#pragma unroll
    for (int t = 0; t < 5; ++t) {
        int idx = tid + t * 256;
        if (idx < n4c) Lc4[idx] = src[idx];
    }
    const bool hasd = (i < NH - 1);
    if (hasd) {
        const float4* srcd = reinterpret_cast<const float4*>(logits + (rowpix + NW) * NC);
#pragma unroll
        for (int t = 0; t < 5; ++t) {
            int idx = tid + t * 256;
            if (idx < 1216) Ld4[idx] = srcd[idx];
        }
    }
    __syncthreads();

    const float* Lc = (const float*)Lc4;
    const float* Ld = (const float*)Ld4;
    // in-block LSE: 257 center (incl. right-halo px) + 256 down
    for (int p = tid; p < 513; p += 256) {
        if (p < 257 || hasd) {
            const float* v = (p < 257) ? &Lc[p * NC] : &Ld[(p - 257) * NC];
            float mx = v[0];
#pragma unroll
            for (int c = 1; c < NC; ++c) mx = fmaxf(mx, v[c]);
            float se = 0.f;
#pragma unroll
            for (int c = 0; c < NC; ++c) se += expf(v[c] - mx);
            float r = mx + logf(se);
            if (p < 257) Mc[p] = r; else Md[p - 257] = r;
        }
    }
    __syncthreads();

    const int j = j0 + tid;
    const size_t pix = rowpix + tid;
    const float lse_c = Mc[tid];
    const float lse_r = Mc[tid + 1];            // garbage when j==NW-1 (masked)
    const float lse_d = hasd ? Md[tid] : 0.f;

    const float* lc = &Lc[tid * NC];
    const float* lr = &Lc[(tid + 1) * NC];      // garbage when j==NW-1 (masked)
    const float* ld = &Ld[tid * NC];            // garbage when !hasd (masked)
    float negH = 0.f, dotr = 0.f, dotd = 0.f;
#pragma unroll
    for (int c = 0; c < NC; ++c) {
        float s = lc[c] - lse_c;
        float p = expf(s);
        negH += p * s;
        dotr += p * lr[c];
        dotd += p * ld[c];
    }
    float kl = 0.f;
    if (hasd) kl += negH + lse_d - dotd;
    if (j < NW - 1) kl += negH + lse_r - dotr;
    klb[pix] = kl;

    int lo = 0, hi = NLAD;
    while (lo < hi) { int mid = (lo + hi) >> 1; if (kl > lad[mid]) lo = mid + 1; else hi = mid; }
    atomicAdd(&lh[lo], 1u);
    __syncthreads();
    if (tid < NLAD + 1 && lh[tid])
        atomicAdd(&hist[(cid & (NREP - 1)) * HSTRIDE + tid], lh[tid]);
}

// ---------------------------------------------------------------------------
// Stage 5: eps selection (exact while-loop replication).
// ---------------------------------------------------------------------------
__global__ void eps_kernel(const unsigned int* __restrict__ hist, float* __restrict__ epsout) {
    __shared__ unsigned int tot[NLAD + 1];
    int k = threadIdx.x;
    if (k < NLAD + 1) {
        unsigned int s = 0;
        for (int r = 0; r < NREP; ++r) s += hist[r * HSTRIDE + k];
        tot[k] = s;
    }
    __syncthreads();
    if (k == 0) {
        float lad[NLAD];
        float e = 1e-5f;
        for (int q = 0; q < NLAD; ++q) { lad[q] = e; e *= 1.2f; }
        unsigned int suf[NLAD + 2];
        suf[NLAD + 1] = 0u;
        for (int q = NLAD; q >= 0; --q) suf[q] = suf[q + 1] + tot[q];
        int K = 0;
        while (K < NLAD - 1 && (float)suf[K + 1] > 2621.44f) K++;
        epsout[0] = lad[K];
    }
}

// ---------------------------------------------------------------------------
// Stage 6a: validity pass (dilation + argmin only) + wave-ballot compaction.
// ---------------------------------------------------------------------------
__global__ __launch_bounds__(256) void valid_kernel(const float* __restrict__ klb,
                                                    const float* __restrict__ dist,
                                                    const float* __restrict__ epsp,
                                                    unsigned int* __restrict__ cnts,
                                                    unsigned int* __restrict__ list) {
    const int tid = threadIdx.x;
    const int b = blockIdx.z;
    const int i = blockIdx.y * TS + (tid >> 4);
    const int j = blockIdx.x * TS + (tid & 15);
    const float eps = epsp[0];
    const float* klp = klb + (size_t)b * NH * NW;
    const float* dp = dist + (size_t)b * NH * NW;

    bool pb = false;
    for (int di = -1; di <= 1; ++di) {
        int ii = i + di; if (ii < 0 || ii >= NH) continue;
        for (int dj = -1; dj <= 1; ++dj) {
            int jj = j + dj; if (jj < 0 || jj >= NW) continue;
            if (klp[(size_t)ii * NW + jj] > eps) pb = true;
        }
    }

    const int dxs[9] = {1, -1, 0, 0, -1, 1, -1, 1, 0};
    const int dys[9] = {0, 0, -1, 1, 1, 1, -1, -1, 0};
    float best = MAXDIS; int gidx = 0;
#pragma unroll
    for (int k = 0; k < 9; ++k) {
        int ii = i + dxs[k], jj = j + dys[k];
        float v = (ii >= 0 && ii < NH && jj >= 0 && jj < NW) ? dp[(size_t)ii * NW + jj] : MAXDIS;
        if (k == 0) { best = v; gidx = 0; }
        else if (v < best) { best = v; gidx = k; }
    }
    bool valid = pb && (gidx != 8);

    const int pix = (b * NH + i) * NW + j;
    const int lane = tid & 63;
    unsigned long long mk = __ballot(valid);
    int cnt = __popcll(mk);
    int flatw = (((blockIdx.z * gridDim.y + blockIdx.y) * gridDim.x + blockIdx.x) << 2) | (tid >> 6);
    int seg = flatw & (NSEG - 1);
    unsigned int base = 0u;
    if (lane == 0 && cnt) base = atomicAdd(&cnts[seg], (unsigned int)cnt);
    base = (unsigned int)__shfl((int)base, 0, 64);
    if (valid) {
        unsigned int off = base + (unsigned int)__popcll(mk & ((1ull << lane) - 1ull));
        if (off < SEGCAP)
            list[seg * SEGCAP + off] = (unsigned int)pix | ((unsigned int)gidx << 20);
    }
}

// ---------------------------------------------------------------------------
// Stage 6b: CE over valid pixels only. 8 lanes per pixel (one per neighbor);
// lse_c computed inline from lc (bit-identical formula; no lsem dependency).
// ---------------------------------------------------------------------------
__global__ __launch_bounds__(256) void dirce_kernel(const float* __restrict__ logits,
                                                    const float* __restrict__ dist,
                                                    const unsigned int* __restrict__ cnts,
                                                    const unsigned int* __restrict__ list,
                                                    float* __restrict__ cearr) {
    const int t = blockIdx.x * 256 + threadIdx.x;
    const int e = t >> 3;                       // entry
    const int d = t & 7;                        // neighbor lane
    const int s = e >> 9;                       // segment (SEGCAP=512)
    const int k = e & (SEGCAP - 1);
    unsigned int cs = cnts[s];
    if ((unsigned int)k >= min(cs, (unsigned int)SEGCAP)) return;
    unsigned int w = list[s * SEGCAP + k];
    const int pix = (int)(w & (NPIX - 1));
    const int gidx = (int)(w >> 20);
    const int j = pix & (NW - 1);
    const int i = (pix >> 9) & (NH - 1);

    const unsigned int DXP = (2u<<0)|(0u<<2)|(1u<<4)|(1u<<6)|(0u<<8)|(2u<<10)|(0u<<12)|(2u<<14);
    const unsigned int DYP = (1u<<0)|(1u<<2)|(0u<<4)|(2u<<6)|(2u<<8)|(2u<<10)|(0u<<12)|(0u<<14);
    const int dx = (int)((DXP >> (2 * d)) & 3u) - 1;
    const int dy = (int)((DYP >> (2 * d)) & 3u) - 1;
    const int ii = i + dx, jj = j + dy;
    const bool inb = (ii >= 0 && ii < NH && jj >= 0 && jj < NW);

    const float* lcp = logits + (size_t)pix * NC;
    float lc[NC];
    float sumlc = 0.f;
#pragma unroll
    for (int c = 0; c < NC; ++c) { lc[c] = lcp[c]; sumlc += lc[c]; }
    float mxc = lc[0];
#pragma unroll
    for (int c = 1; c < NC; ++c) mxc = fmaxf(mxc, lc[c]);
    float sec = 0.f;
#pragma unroll
    for (int c = 0; c < NC; ++c) sec += expf(lc[c] - mxc);
    const float lse_c = mxc + logf(sec);

    float klm;
    if (inb) {
        const int npix = pix + dx * NW + dy;
        const float* lnp = logits + (size_t)npix * NC;
        float tv[NC], ev[NC];
#pragma unroll
        for (int c = 0; c < NC; ++c) tv[c] = lnp[c];
        float mxn = tv[0];
#pragma unroll
        for (int c = 1; c < NC; ++c) mxn = fmaxf(mxn, tv[c]);
        float sen = 0.f;
#pragma unroll
        for (int c = 0; c < NC; ++c) {
            float sv = tv[c] - mxn;
            float eexp = expf(sv);
            ev[c] = eexp; sen += eexp; tv[c] = sv;
        }
        float ls = logf(sen);
        float inv = 1.f / sen;
        float negH = 0.f, dot = 0.f;
#pragma unroll
        for (int c = 0; c < NC; ++c) {
            float p = ev[c] * inv;
            negH += p * (tv[c] - ls);
            dot += p * lc[c];
        }
        klm = negH + lse_c - dot;
    } else {
        klm = -logf(19.f) + lse_c - sumlc / 19.f;
    }

    float m2 = klm;
#pragma unroll
    for (int o = 4; o > 0; o >>= 1) m2 = fmaxf(m2, __shfl_xor(m2, o, 8));
    float ex = expf(klm - m2);
    float s2 = ex;
#pragma unroll
    for (int o = 4; o > 0; o >>= 1) s2 += __shfl_xor(s2, o, 8);
    float lse = m2 + logf(s2);
    float lp = klm - lse;
    float slp = lp;
#pragma unroll
    for (int o = 4; o > 0; o >>= 1) slp += __shfl_xor(slp, o, 8);
    float kg = (d == gidx) ? lp : 0.f;
#pragma unroll
    for (int o = 4; o > 0; o >>= 1) kg += __shfl_xor(kg, o, 8);

    if (d == 0) {
        float ce = -(0.2f / 8.f) * slp - 0.8f * kg;
        float wgt = fminf(dist[pix], 20.f) / 20.f;
        cearr[pix] = ce * wgt;
    }
}

// ---------------------------------------------------------------------------
// Stage 7a: block-tree reduce of dense cearr (1024 floats/block, fixed order).
// ---------------------------------------------------------------------------
__global__ __launch_bounds__(256) void redA_kernel(const float4* __restrict__ cearr4,
                                                   float* __restrict__ partials) {
    __shared__ float r[256];
    const int tid = threadIdx.x;
    float4 v = cearr4[(size_t)blockIdx.x * 256 + tid];
    r[tid] = (v.x + v.y) + (v.z + v.w);
    __syncthreads();
    for (int s = 128; s > 0; s >>= 1) {
        if (tid < s) r[tid] += r[tid + s];
        __syncthreads();
    }
    if (tid == 0) partials[blockIdx.x] = r[0];
}

// ---------------------------------------------------------------------------
// Stage 7b: final: sum partials + valid count -> loss.
// ---------------------------------------------------------------------------
__global__ __launch_bounds__(256) void redB_kernel(const float* __restrict__ partials,
                                                   const unsigned int* __restrict__ cnts,
                                                   float* __restrict__ out) {
    __shared__ float r[256];
    const int tid = threadIdx.x;
    r[tid] = partials[tid] + partials[tid + 256] + partials[tid + 512] + partials[tid + 768];
    __syncthreads();
    for (int s = 128; s > 0; s >>= 1) {
        if (tid < s) r[tid] += r[tid + s];
        __syncthreads();
    }
    if (tid == 0) {
        unsigned int vf = 0;
        for (int q = 0; q < NSEG; ++q) vf += cnts[q];
        out[0] = r[0] / fmaxf((float)vf, 1.f);
    }
}

extern "C" void kernel_launch(void* const* d_in, const int* in_sizes, int n_in,
                              void* d_out, int out_size, void* d_ws, size_t ws_size,
                              hipStream_t stream) {
    const float* logits = (const float*)d_in[0];
    const int* target = (const int*)d_in[1];
    float* out = (float*)d_out;

    float* fws = (float*)d_ws;
    float* distb = fws;                         // NPIX floats
    float* klb = fws + NPIX;                    // NPIX floats
    float* cearr = fws + 2 * (size_t)NPIX;      // NPIX floats
    unsigned int* hist = (unsigned int*)(fws + 3 * (size_t)NPIX);   // NREP*HSTRIDE
    unsigned int* cnts = hist + NREP * HSTRIDE;                     // NSEG
    float* epsb = (float*)(cnts + NSEG);                            // 1 (+pad)
    unsigned int* list = (unsigned int*)(epsb + 64);                // NSEG*SEGCAP
    float* partials = (float*)(list + NSEG * SEGCAP);               // 1024
    unsigned int* maskw = (unsigned int*)(partials + 1024);         // NB*NWRD*NW

    // bound zeroes cearr + hist + cnts (block 0); stream order guards consumers
    bound_kernel<<<NB * NWRD * NW / 64, 64, 0, stream>>>(target, maskw,
                                                         (float4*)cearr, hist);
    vdistrow_kernel<<<NB * NH, 512, 0, stream>>>(maskw, distb);

    klhist_kernel<<<NB * NH * 2, 256, 0, stream>>>(logits, klb, hist);
    eps_kernel<<<1, 256, 0, stream>>>(hist, epsb);

    dim3 tiles(NW / TS, NH / TS, NB);
    valid_kernel<<<tiles, 256, 0, stream>>>(klb, distb, epsb, cnts, list);
    dirce_kernel<<<NSEG * SEGCAP * 8 / 256, 256, 0, stream>>>(logits, distb,
                                                              cnts, list, cearr);
    redA_kernel<<<1024, 256, 0, stream>>>((const float4*)cearr, partials);
    redB_kernel<<<1, 256, 0, stream>>>(partials, cnts, out);
}

// Round 9
// 110.051 us; speedup vs baseline: 1.1332x; 1.1332x over previous
//
#include <hip/hip_runtime.h>
#include <math.h>

#define NB 4
#define NH 512
#define NW 512
#define NC 19
#define NPIX (NB*NH*NW)
#define TS 16
#define NLAD 128
#define INF6 1.0e6f
#define MAXDIS 1.0e5f
#define NWRD 16          // 512 rows / 32 bits
#define NREP 8           // histogram replicas
#define HSTRIDE 132      // padded per-replica stride (129 bins)
#define NSEG 128         // compaction segments
#define SEGCAP 512       // entries per segment (expected max ~250)
#define NZERO (NREP*HSTRIDE + NSEG)   // hist + cnts words zeroed by bound blk 0

// ---------------------------------------------------------------------------
// Stage 1a: boundary bitmasks. One thread per (b, word, column).
// Also zero-fills cearr (4 MB, coalesced float4) and hist+cnts (block 0).
// ---------------------------------------------------------------------------
__global__ __launch_bounds__(64) void bound_kernel(const int* __restrict__ tgt,
                                                   unsigned int* __restrict__ maskw,
                                                   float4* __restrict__ cearr4,
                                                   unsigned int* __restrict__ zbuf) {
    int cidx = blockIdx.x * 64 + threadIdx.x;           // [b][w][j], 32768 total
    const float4 z4 = make_float4(0.f, 0.f, 0.f, 0.f);
#pragma unroll
    for (int k = 0; k < 8; ++k) cearr4[cidx + k * 32768] = z4;   // NPIX/4 entries
    if (blockIdx.x == 0) {
        for (int k = threadIdx.x; k < NZERO; k += 64) zbuf[k] = 0u;
    }
    int j = cidx & (NW - 1);
    int w = (cidx >> 9) & (NWRD - 1);
    int b = cidx >> 13;
    const int* t = tgt + (size_t)b * NH * NW;
    unsigned int mask = 0u;
    int i0 = w * 32;
    int cur = t[(size_t)i0 * NW + j];
    for (int k = 0; k < 32; ++k) {
        int i = i0 + k;
        int nxt = (i + 1 < NH) ? t[(size_t)(i + 1) * NW + j] : cur;
        bool bnd = (cur == 255);
        if (i + 1 < NH && nxt != cur) bnd = true;
        if (j + 1 < NW && t[(size_t)i * NW + j + 1] != cur) bnd = true;
        if (bnd) mask |= (1u << k);
        cur = nxt;
    }
    maskw[cidx] = mask;
}

// ---------------------------------------------------------------------------
// Stage 1b+2 fused: block per row; batch mask set in LDS; nearest-set-bit ->
// G^2 -> row min-plus transform -> final dist.
// ---------------------------------------------------------------------------
__global__ __launch_bounds__(512) void vdistrow_kernel(const unsigned int* __restrict__ maskw,
                                                       float* __restrict__ dist) {
    __shared__ unsigned int smw[NWRD][NW];   // 32 KB: all masks of this batch
    __shared__ float s[NW];
    __shared__ unsigned int anyw[8];
    const int tid = threadIdx.x;             // = column j
    const int row = blockIdx.x;              // b*NH + i
    const int b = row >> 9;
    const int i = row & (NH - 1);
    const unsigned int* mcol = maskw + (size_t)b * NWRD * NW;
    unsigned int acc = 0u;
#pragma unroll
    for (int w = 0; w < NWRD; ++w) {
        unsigned int v = mcol[w * NW + tid];
        smw[w][tid] = v;
        acc |= v;
    }
    unsigned long long bal = __ballot(acc != 0u);
    if ((tid & 63) == 0) anyw[tid >> 6] = (bal != 0ull) ? 1u : 0u;

    const int wi = i >> 5, bi = i & 31;
    int down = 1 << 20;
    unsigned int m = smw[wi][tid] & ((2u << bi) - 1u);   // bits 0..bi
    if (m) down = bi - (31 - __clz(m));
    else {
        for (int w = wi - 1; w >= 0; --w) {
            unsigned int mm = smw[w][tid];
            if (mm) { down = bi + 32 * (wi - w) - (31 - __clz(mm)); break; }
        }
    }
    int up = 1 << 20;
    unsigned int mu = smw[wi][tid] & ~((1u << bi) - 1u); // bits bi..31
    if (mu) up = (__ffs(mu) - 1) - bi;
    else {
        for (int w = wi + 1; w < NWRD; ++w) {
            unsigned int mm = smw[w][tid];
            if (mm) { up = 32 * (w - wi) + (__ffs(mm) - 1) - bi; break; }
        }
    }
    int gi = min(down, up);
    float G = (gi >= (1 << 20)) ? INF6 : (float)gi;
    s[tid] = G * G;
    __syncthreads();
    bool has = (anyw[0] | anyw[1] | anyw[2] | anyw[3] |
                anyw[4] | anyw[5] | anyw[6] | anyw[7]) != 0u;
    float best = s[tid];
    for (int r = 1; r < NW; ++r) {
        float rr = (float)(r * r);
        if (rr >= best) break;
        int jl = tid - r, jr = tid + r;
        if (jl >= 0) best = fminf(best, s[jl] + rr);
        if (jr < NW) best = fminf(best, s[jr] + rr);
    }
    dist[(size_t)row * NW + tid] = has ? fmaxf(sqrtf(best) - 1.f, 0.f) : 0.f;
}

// ---------------------------------------------------------------------------
// Stage 3a: per-pixel log-sum-exp map (float4-staged to LDS, reg reduce).
// Each LSE computed exactly once.
// ---------------------------------------------------------------------------
__global__ __launch_bounds__(256) void lse_kernel(const float* __restrict__ logits,
                                                  float* __restrict__ lsem) {
    __shared__ float4 S4[1216];                 // 256*19 floats
    const int tid = threadIdx.x;
    const size_t pix0 = (size_t)blockIdx.x * 256;
    const float4* src = reinterpret_cast<const float4*>(logits + pix0 * NC);
#pragma unroll
    for (int t = 0; t < 5; ++t) {
        int idx = tid + t * 256;
        if (idx < 1216) S4[idx] = src[idx];
    }
    __syncthreads();
    const float* L = (const float*)S4;
    const float* v = &L[tid * NC];
    float mx = v[0];
#pragma unroll
    for (int c = 1; c < NC; ++c) mx = fmaxf(mx, v[c]);
    float se = 0.f;
#pragma unroll
    for (int c = 0; c < NC; ++c) se += expf(v[c] - mx);
    lsem[pix0 + tid] = mx + logf(se);
}

// ---------------------------------------------------------------------------
// Stage 3b: kl map + fused 8-replica histogram. NO logits LDS staging:
// per-thread direct loads of lc/lr/ld (coalesced cache lines, L1/L2 reuse),
// LSEs from lsem. 19 expf/thread. LDS = 0.6 KB -> max occupancy.
// ---------------------------------------------------------------------------
__global__ __launch_bounds__(256) void klhist_kernel(const float* __restrict__ logits,
                                                     const float* __restrict__ lsem,
                                                     float* __restrict__ klb,
                                                     unsigned int* __restrict__ hist) {
    __shared__ float lad[NLAD];
    __shared__ unsigned int lh[NLAD + 1];
    const int tid = threadIdx.x;
    const int cid = blockIdx.x;
    if (tid == 0) {
        float e = 1e-5f;
        for (int k = 0; k < NLAD; ++k) { lad[k] = e; e *= 1.2f; }
    }
    if (tid < NLAD + 1) lh[tid] = 0u;
    __syncthreads();

    const int j0 = (cid & 1) * 256;
    const int i = (cid >> 1) & (NH - 1);
    const int b = cid >> 10;
    const int j = j0 + tid;
    const size_t pix = (size_t)(b * NH + i) * NW + j;
    const bool hasd = (i < NH - 1);
    const bool hasr = (j < NW - 1);

    const float lse_c = lsem[pix];
    const float lse_r = hasr ? lsem[pix + 1] : 0.f;
    const float lse_d = hasd ? lsem[pix + NW] : 0.f;

    const float* lcp = logits + pix * NC;
    float lc[NC], lr[NC], ld[NC];
#pragma unroll
    for (int c = 0; c < NC; ++c) lc[c] = lcp[c];
    if (hasr) {
#pragma unroll
        for (int c = 0; c < NC; ++c) lr[c] = lcp[NC + c];
    } else {
#pragma unroll
        for (int c = 0; c < NC; ++c) lr[c] = 0.f;
    }
    if (hasd) {
        const float* ldp = lcp + (size_t)NW * NC;
#pragma unroll
        for (int c = 0; c < NC; ++c) ld[c] = ldp[c];
    } else {
#pragma unroll
        for (int c = 0; c < NC; ++c) ld[c] = 0.f;
    }

    float negH = 0.f, dotr = 0.f, dotd = 0.f;
#pragma unroll
    for (int c = 0; c < NC; ++c) {
        float s = lc[c] - lse_c;
        float p = expf(s);
        negH += p * s;
        dotr += p * lr[c];
        dotd += p * ld[c];
    }
    float kl = 0.f;
    if (hasd) kl += negH + lse_d - dotd;
    if (hasr) kl += negH + lse_r - dotr;
    klb[pix] = kl;

    int lo = 0, hi = NLAD;
    while (lo < hi) { int mid = (lo + hi) >> 1; if (kl > lad[mid]) lo = mid + 1; else hi = mid; }
    atomicAdd(&lh[lo], 1u);
    __syncthreads();
    if (tid < NLAD + 1 && lh[tid])
        atomicAdd(&hist[(cid & (NREP - 1)) * HSTRIDE + tid], lh[tid]);
}

// ---------------------------------------------------------------------------
// Stage 5: eps selection (exact while-loop replication).
// ---------------------------------------------------------------------------
__global__ void eps_kernel(const unsigned int* __restrict__ hist, float* __restrict__ epsout) {
    __shared__ unsigned int tot[NLAD + 1];
    int k = threadIdx.x;
    if (k < NLAD + 1) {
        unsigned int s = 0;
        for (int r = 0; r < NREP; ++r) s += hist[r * HSTRIDE + k];
        tot[k] = s;
    }
    __syncthreads();
    if (k == 0) {
        float lad[NLAD];
        float e = 1e-5f;
        for (int q = 0; q < NLAD; ++q) { lad[q] = e; e *= 1.2f; }
        unsigned int suf[NLAD + 2];
        suf[NLAD + 1] = 0u;
        for (int q = NLAD; q >= 0; --q) suf[q] = suf[q + 1] + tot[q];
        int K = 0;
        while (K < NLAD - 1 && (float)suf[K + 1] > 2621.44f) K++;
        epsout[0] = lad[K];
    }
}

// ---------------------------------------------------------------------------
// Stage 6a: validity pass (dilation + argmin only) + wave-ballot compaction.
// ---------------------------------------------------------------------------
__global__ __launch_bounds__(256) void valid_kernel(const float* __restrict__ klb,
                                                    const float* __restrict__ dist,
                                                    const float* __restrict__ epsp,
                                                    unsigned int* __restrict__ cnts,
                                                    unsigned int* __restrict__ list) {
    const int tid = threadIdx.x;
    const int b = blockIdx.z;
    const int i = blockIdx.y * TS + (tid >> 4);
    const int j = blockIdx.x * TS + (tid & 15);
    const float eps = epsp[0];
    const float* klp = klb + (size_t)b * NH * NW;
    const float* dp = dist + (size_t)b * NH * NW;

    bool pb = false;
    for (int di = -1; di <= 1; ++di) {
        int ii = i + di; if (ii < 0 || ii >= NH) continue;
        for (int dj = -1; dj <= 1; ++dj) {
            int jj = j + dj; if (jj < 0 || jj >= NW) continue;
            if (klp[(size_t)ii * NW + jj] > eps) pb = true;
        }
    }

    const int dxs[9] = {1, -1, 0, 0, -1, 1, -1, 1, 0};
    const int dys[9] = {0, 0, -1, 1, 1, 1, -1, -1, 0};
    float best = MAXDIS; int gidx = 0;
#pragma unroll
    for (int k = 0; k < 9; ++k) {
        int ii = i + dxs[k], jj = j + dys[k];
        float v = (ii >= 0 && ii < NH && jj >= 0 && jj < NW) ? dp[(size_t)ii * NW + jj] : MAXDIS;
        if (k == 0) { best = v; gidx = 0; }
        else if (v < best) { best = v; gidx = k; }
    }
    bool valid = pb && (gidx != 8);

    const int pix = (b * NH + i) * NW + j;
    const int lane = tid & 63;
    unsigned long long mk = __ballot(valid);
    int cnt = __popcll(mk);
    int flatw = (((blockIdx.z * gridDim.y + blockIdx.y) * gridDim.x + blockIdx.x) << 2) | (tid >> 6);
    int seg = flatw & (NSEG - 1);
    unsigned int base = 0u;
    if (lane == 0 && cnt) base = atomicAdd(&cnts[seg], (unsigned int)cnt);
    base = (unsigned int)__shfl((int)base, 0, 64);
    if (valid) {
        unsigned int off = base + (unsigned int)__popcll(mk & ((1ull << lane) - 1ull));
        if (off < SEGCAP)
            list[seg * SEGCAP + off] = (unsigned int)pix | ((unsigned int)gidx << 20);
    }
}

// ---------------------------------------------------------------------------
// Stage 6b: CE over valid pixels only. 8 lanes per pixel (one per neighbor);
// lse_c/lse_n from lsem.
// ---------------------------------------------------------------------------
__global__ __launch_bounds__(256) void dirce_kernel(const float* __restrict__ logits,
                                                    const float* __restrict__ lsem,
                                                    const float* __restrict__ dist,
                                                    const unsigned int* __restrict__ cnts,
                                                    const unsigned int* __restrict__ list,
                                                    float* __restrict__ cearr) {
    const int t = blockIdx.x * 256 + threadIdx.x;
    const int e = t >> 3;                       // entry
    const int d = t & 7;                        // neighbor lane
    const int s = e >> 9;                       // segment (SEGCAP=512)
    const int k = e & (SEGCAP - 1);
    unsigned int cs = cnts[s];
    if ((unsigned int)k >= min(cs, (unsigned int)SEGCAP)) return;
    unsigned int w = list[s * SEGCAP + k];
    const int pix = (int)(w & (NPIX - 1));
    const int gidx = (int)(w >> 20);
    const int j = pix & (NW - 1);
    const int i = (pix >> 9) & (NH - 1);

    const unsigned int DXP = (2u<<0)|(0u<<2)|(1u<<4)|(1u<<6)|(0u<<8)|(2u<<10)|(0u<<12)|(2u<<14);
    const unsigned int DYP = (1u<<0)|(1u<<2)|(0u<<4)|(2u<<6)|(2u<<8)|(2u<<10)|(0u<<12)|(0u<<14);
    const int dx = (int)((DXP >> (2 * d)) & 3u) - 1;
    const int dy = (int)((DYP >> (2 * d)) & 3u) - 1;
    const int ii = i + dx, jj = j + dy;
    const bool inb = (ii >= 0 && ii < NH && jj >= 0 && jj < NW);

    const float lse_c = lsem[pix];
    const float* lcp = logits + (size_t)pix * NC;
    float lc[NC];
    float sumlc = 0.f;
#pragma unroll
    for (int c = 0; c < NC; ++c) { lc[c] = lcp[c]; sumlc += lc[c]; }

    float klm;
    if (inb) {
        const int npix = pix + dx * NW + dy;
        const float lse_n = lsem[npix];
        const float* lnp = logits + (size_t)npix * NC;
        float negH = 0.f, dot = 0.f;
#pragma unroll
        for (int c = 0; c < NC; ++c) {
            float sv = lnp[c] - lse_n;
            float p = expf(sv);
            negH += p * sv;
            dot += p * lc[c];
        }
        klm = negH + lse_c - dot;
    } else {
        klm = -logf(19.f) + lse_c - sumlc / 19.f;
    }

    float m2 = klm;
#pragma unroll
    for (int o = 4; o > 0; o >>= 1) m2 = fmaxf(m2, __shfl_xor(m2, o, 8));
    float ex = expf(klm - m2);
    float s2 = ex;
#pragma unroll
    for (int o = 4; o > 0; o >>= 1) s2 += __shfl_xor(s2, o, 8);
    float lse = m2 + logf(s2);
    float lp = klm - lse;
    float slp = lp;
#pragma unroll
    for (int o = 4; o > 0; o >>= 1) slp += __shfl_xor(slp, o, 8);
    float kg = (d == gidx) ? lp : 0.f;
#pragma unroll
    for (int o = 4; o > 0; o >>= 1) kg += __shfl_xor(kg, o, 8);

    if (d == 0) {
        float ce = -(0.2f / 8.f) * slp - 0.8f * kg;
        float wgt = fminf(dist[pix], 20.f) / 20.f;
        cearr[pix] = ce * wgt;
    }
}

// ---------------------------------------------------------------------------
// Stage 7a: block-tree reduce of dense cearr (1024 floats/block, fixed order).
// ---------------------------------------------------------------------------
__global__ __launch_bounds__(256) void redA_kernel(const float4* __restrict__ cearr4,
                                                   float* __restrict__ partials) {
    __shared__ float r[256];
    const int tid = threadIdx.x;
    float4 v = cearr4[(size_t)blockIdx.x * 256 + tid];
    r[tid] = (v.x + v.y) + (v.z + v.w);
    __syncthreads();
    for (int s = 128; s > 0; s >>= 1) {
        if (tid < s) r[tid] += r[tid + s];
        __syncthreads();
    }
    if (tid == 0) partials[blockIdx.x] = r[0];
}

// ---------------------------------------------------------------------------
// Stage 7b: final: sum partials + valid count -> loss.
// ---------------------------------------------------------------------------
__global__ __launch_bounds__(256) void redB_kernel(const float* __restrict__ partials,
                                                   const unsigned int* __restrict__ cnts,
                                                   float* __restrict__ out) {
    __shared__ float r[256];
    const int tid = threadIdx.x;
    r[tid] = partials[tid] + partials[tid + 256] + partials[tid + 512] + partials[tid + 768];
    __syncthreads();
    for (int s = 128; s > 0; s >>= 1) {
        if (tid < s) r[tid] += r[tid + s];
        __syncthreads();
    }
    if (tid == 0) {
        unsigned int vf = 0;
        for (int q = 0; q < NSEG; ++q) vf += cnts[q];
        out[0] = r[0] / fmaxf((float)vf, 1.f);
    }
}

extern "C" void kernel_launch(void* const* d_in, const int* in_sizes, int n_in,
                              void* d_out, int out_size, void* d_ws, size_t ws_size,
                              hipStream_t stream) {
    const float* logits = (const float*)d_in[0];
    const int* target = (const int*)d_in[1];
    float* out = (float*)d_out;

    float* fws = (float*)d_ws;
    float* distb = fws;                         // NPIX floats
    float* klb = fws + NPIX;                    // NPIX floats
    float* lsem = fws + 2 * (size_t)NPIX;       // NPIX floats
    float* cearr = fws + 3 * (size_t)NPIX;      // NPIX floats
    unsigned int* hist = (unsigned int*)(fws + 4 * (size_t)NPIX);   // NREP*HSTRIDE
    unsigned int* cnts = hist + NREP * HSTRIDE;                     // NSEG
    float* epsb = (float*)(cnts + NSEG);                            // 1 (+pad)
    unsigned int* list = (unsigned int*)(epsb + 64);                // NSEG*SEGCAP
    float* partials = (float*)(list + NSEG * SEGCAP);               // 1024
    unsigned int* maskw = (unsigned int*)(partials + 1024);         // NB*NWRD*NW

    // bound zeroes cearr + hist + cnts (block 0); stream order guards consumers
    bound_kernel<<<NB * NWRD * NW / 64, 64, 0, stream>>>(target, maskw,
                                                         (float4*)cearr, hist);
    vdistrow_kernel<<<NB * NH, 512, 0, stream>>>(maskw, distb);

    lse_kernel<<<NPIX / 256, 256, 0, stream>>>(logits, lsem);
    klhist_kernel<<<NB * NH * 2, 256, 0, stream>>>(logits, lsem, klb, hist);
    eps_kernel<<<1, 256, 0, stream>>>(hist, epsb);

    dim3 tiles(NW / TS, NH / TS, NB);
    valid_kernel<<<tiles, 256, 0, stream>>>(klb, distb, epsb, cnts, list);
    dirce_kernel<<<NSEG * SEGCAP * 8 / 256, 256, 0, stream>>>(logits, lsem, distb,
                                                              cnts, list, cearr);
    redA_kernel<<<1024, 256, 0, stream>>>((const float4*)cearr, partials);
    redB_kernel<<<1, 256, 0, stream>>>(partials, cnts, out);
}